// Round 1
// baseline (420.946 us; speedup 1.0000x reference)
//
#include <hip/hip_runtime.h>
#include <math.h>

// Problem constants: B=16, T=1024, C=768, H=128
#define BT_ROWS 16384      // B*T
#define NEMBD   768
#define HDIM    128

// ---------------------------------------------------------------------------
// Kernel 1: QKV projection. out = x @ W for W in {Wk, Wq, Wv}.
// Block: 256 threads computes a 64x128 tile of one output. Grid (256, 3).
// fp32, LDS-tiled K by 32, 4x8 register blocking per thread.
// ---------------------------------------------------------------------------
__global__ __launch_bounds__(256) void qkv_gemm(
    const float* __restrict__ x,
    const float* __restrict__ Wk, const float* __restrict__ Wq,
    const float* __restrict__ Wv,
    float* __restrict__ kws, float* __restrict__ qws, float* __restrict__ vws)
{
    const float* W;
    float* out;
    if (blockIdx.y == 0)      { W = Wk; out = kws; }
    else if (blockIdx.y == 1) { W = Wq; out = qws; }
    else                      { W = Wv; out = vws; }

    // As stride 36 (pad 32->36, keeps 16B alignment, breaks bank aliasing)
    __shared__ float As[64 * 36];
    __shared__ float Bs[32 * 128];

    const int tid = threadIdx.x;
    const int m0  = blockIdx.x * 64;
    const int ty  = tid >> 4;   // 0..15 -> 4 rows each
    const int tx  = tid & 15;   // 0..15 -> 8 cols each (stride 16)

    float acc[4][8];
    #pragma unroll
    for (int i = 0; i < 4; ++i)
        #pragma unroll
        for (int j = 0; j < 8; ++j) acc[i][j] = 0.f;

    for (int k0 = 0; k0 < NEMBD; k0 += 32) {
        __syncthreads();
        // stage x tile: 64 rows x 32 k  (512 float4, 2 per thread)
        #pragma unroll
        for (int i = 0; i < 2; ++i) {
            int idx = tid + i * 256;          // 0..511
            int row = idx >> 3, k4 = idx & 7;
            float4 v = *(const float4*)&x[(size_t)(m0 + row) * NEMBD + k0 + k4 * 4];
            *(float4*)&As[row * 36 + k4 * 4] = v;
        }
        // stage W tile: 32 k x 128 n  (1024 float4, 4 per thread)
        #pragma unroll
        for (int i = 0; i < 4; ++i) {
            int idx = tid + i * 256;          // 0..1023
            int kk = idx >> 5, n4 = idx & 31;
            float4 v = *(const float4*)&W[(size_t)(k0 + kk) * HDIM + n4 * 4];
            *(float4*)&Bs[kk * HDIM + n4 * 4] = v;
        }
        __syncthreads();

        #pragma unroll 8
        for (int kk = 0; kk < 32; ++kk) {
            float a[4], b[8];
            #pragma unroll
            for (int ri = 0; ri < 4; ++ri) a[ri] = As[(4 * ty + ri) * 36 + kk];
            #pragma unroll
            for (int ci = 0; ci < 8; ++ci) b[ci] = Bs[kk * HDIM + tx + 16 * ci];
            #pragma unroll
            for (int ri = 0; ri < 4; ++ri)
                #pragma unroll
                for (int ci = 0; ci < 8; ++ci)
                    acc[ri][ci] = fmaf(a[ri], b[ci], acc[ri][ci]);
        }
    }

    #pragma unroll
    for (int ri = 0; ri < 4; ++ri)
        #pragma unroll
        for (int ci = 0; ci < 8; ++ci)
            out[(size_t)(m0 + 4 * ty + ri) * HDIM + tx + 16 * ci] = acc[ri][ci];
}

// ---------------------------------------------------------------------------
// Kernel 2: flash attention (fp32, online softmax).
// Grid (16, 16): blockIdx.x = pair p -> q-tiles {p, 31-p} (32 rows each),
// blockIdx.y = batch. Work per block = (p+1)+(32-p) = 33 key-tile units,
// perfectly balanced across the 256 blocks (1 per CU).
// Row state (m, l) lives in registers: row = tid>>3 for BOTH score and O
// stages, replicated consistently across the 8 lanes of a row group.
// ---------------------------------------------------------------------------
__global__ __launch_bounds__(256) void attn(
    const float* __restrict__ qws, const float* __restrict__ kws,
    const float* __restrict__ vws, float* __restrict__ out)
{
    __shared__ float Qs[32 * 132];   // stride 132 = 128+4 (16B-aligned pad)
    __shared__ float Ks[32 * 132];
    __shared__ float Vs[32 * 132];
    __shared__ float Ps[32 * 36];

    const int tid = threadIdx.x;
    const int b   = blockIdx.y;
    const int p   = blockIdx.x;            // 0..15
    const float scale = 0.03608439182435161f;  // 768^-0.5

    const int r  = tid >> 3;               // row within tile, 0..31
    const int cg = tid & 7;                // col group, 0..7

    for (int half = 0; half < 2; ++half) {
        const int qt = (half == 0) ? p : (31 - p);

        // stage Q tile, scale folded in
        const float* qbase = qws + ((size_t)b * 1024 + qt * 32) * HDIM;
        __syncthreads();   // protect Qs/Ps/Vs from previous half's readers
        #pragma unroll
        for (int i = 0; i < 4; ++i) {
            int idx = tid + i * 256;
            int row = idx >> 5, c4 = idx & 31;
            float4 v = *(const float4*)&qbase[(size_t)row * HDIM + c4 * 4];
            v.x *= scale; v.y *= scale; v.z *= scale; v.w *= scale;
            *(float4*)&Qs[row * 132 + c4 * 4] = v;
        }

        float m_r = -1e30f, l_r = 0.f;
        float4 o[4];
        #pragma unroll
        for (int j = 0; j < 4; ++j) o[j] = make_float4(0.f, 0.f, 0.f, 0.f);

        const int rg = qt * 32 + r;        // global query row within batch

        for (int st = 0; st <= qt; ++st) {
            __syncthreads();               // prev iter's O-update done reading Ks/Vs/Ps
            const float* kbase = kws + ((size_t)b * 1024 + st * 32) * HDIM;
            const float* vbase = vws + ((size_t)b * 1024 + st * 32) * HDIM;
            #pragma unroll
            for (int i = 0; i < 4; ++i) {
                int idx = tid + i * 256;
                int row = idx >> 5, c4 = idx & 31;
                *(float4*)&Ks[row * 132 + c4 * 4] =
                    *(const float4*)&kbase[(size_t)row * HDIM + c4 * 4];
                *(float4*)&Vs[row * 132 + c4 * 4] =
                    *(const float4*)&vbase[(size_t)row * HDIM + c4 * 4];
            }
            __syncthreads();

            // scores: row r vs cols c0..c0+3
            const int c0 = cg * 4;
            float sacc[4] = {0.f, 0.f, 0.f, 0.f};
            const float4* qrow = (const float4*)&Qs[r * 132];
            #pragma unroll 8
            for (int k4 = 0; k4 < 32; ++k4) {
                float4 qv = qrow[k4];
                #pragma unroll
                for (int j = 0; j < 4; ++j) {
                    float4 kv = *(const float4*)&Ks[(c0 + j) * 132 + k4 * 4];
                    sacc[j] += qv.x * kv.x + qv.y * kv.y + qv.z * kv.z + qv.w * kv.w;
                }
            }
            if (st == qt) {                // causal mask on diagonal tile
                #pragma unroll
                for (int j = 0; j < 4; ++j)
                    if (st * 32 + c0 + j > rg) sacc[j] = -1e30f;
            }

            // online softmax: reduce over the 8 lanes of this row group
            float tmax = fmaxf(fmaxf(sacc[0], sacc[1]), fmaxf(sacc[2], sacc[3]));
            #pragma unroll
            for (int off = 1; off < 8; off <<= 1)
                tmax = fmaxf(tmax, __shfl_xor(tmax, off));
            float m_new = fmaxf(m_r, tmax);
            float pv[4], psum = 0.f;
            #pragma unroll
            for (int j = 0; j < 4; ++j) {
                pv[j] = __expf(sacc[j] - m_new);   // masked: exp(-1e30)=0
                psum += pv[j];
            }
            #pragma unroll
            for (int off = 1; off < 8; off <<= 1)
                psum += __shfl_xor(psum, off);
            float alpha = __expf(m_r - m_new);
            m_r = m_new;
            l_r = l_r * alpha + psum;
            *(float4*)&Ps[r * 36 + c0] = make_float4(pv[0], pv[1], pv[2], pv[3]);
            __syncthreads();

            // O update: o = o*alpha + P @ V   (cols cg*4 + 32*j)
            #pragma unroll
            for (int j = 0; j < 4; ++j) {
                o[j].x *= alpha; o[j].y *= alpha; o[j].z *= alpha; o[j].w *= alpha;
            }
            #pragma unroll 4
            for (int s = 0; s < 32; ++s) {
                float pp = Ps[r * 36 + s];
                #pragma unroll
                for (int j = 0; j < 4; ++j) {
                    float4 vv = *(const float4*)&Vs[s * 132 + cg * 4 + 32 * j];
                    o[j].x = fmaf(pp, vv.x, o[j].x);
                    o[j].y = fmaf(pp, vv.y, o[j].y);
                    o[j].z = fmaf(pp, vv.z, o[j].z);
                    o[j].w = fmaf(pp, vv.w, o[j].w);
                }
            }
        }

        const float inv = 1.f / l_r;
        float* obase = out + ((size_t)b * 1024 + qt * 32 + r) * HDIM;
        #pragma unroll
        for (int j = 0; j < 4; ++j) {
            float4 v = o[j];
            v.x *= inv; v.y *= inv; v.z *= inv; v.w *= inv;
            *(float4*)&obase[cg * 4 + 32 * j] = v;
        }
    }
}

// ---------------------------------------------------------------------------
extern "C" void kernel_launch(void* const* d_in, const int* in_sizes, int n_in,
                              void* d_out, int out_size, void* d_ws, size_t ws_size,
                              hipStream_t stream)
{
    const float* x  = (const float*)d_in[0];
    const float* Wk = (const float*)d_in[1];
    const float* Wq = (const float*)d_in[2];
    const float* Wv = (const float*)d_in[3];
    float* outp = (float*)d_out;

    // workspace: k, q, v each B*T*H fp32 = 8 MB (24 MB total)
    const size_t mat = (size_t)BT_ROWS * HDIM;   // 2,097,152 floats
    float* kws = (float*)d_ws;
    float* qws = kws + mat;
    float* vws = qws + mat;

    qkv_gemm<<<dim3(BT_ROWS / 64, 3), 256, 0, stream>>>(x, Wk, Wq, Wv, kws, qws, vws);
    attn<<<dim3(16, 16), 256, 0, stream>>>(qws, kws, vws, outp);
}

// Round 2
// 148.895 us; speedup vs baseline: 2.8271x; 2.8271x over previous
//
#include <hip/hip_runtime.h>
#include <math.h>

// B=16, T=1024, C=768, H=128
#define NTOK   16384     // B*T
#define NEMBD  768
#define HDIM   128

typedef __attribute__((ext_vector_type(8)))  short short8;
typedef __attribute__((ext_vector_type(16))) float floatx16;

#define MFMA32(a,b,c) __builtin_amdgcn_mfma_f32_32x32x16_bf16(a,b,c,0,0,0)

__device__ __forceinline__ unsigned short f2bf(float f) {
    unsigned u = __float_as_uint(f);
    u += 0x7fff + ((u >> 16) & 1);          // RNE
    return (unsigned short)(u >> 16);
}
__device__ __forceinline__ unsigned pack2(float a, float b) {
    return (unsigned)f2bf(a) | ((unsigned)f2bf(b) << 16);
}
__device__ __forceinline__ void gl_lds16(const void* gptr, void* lptr) {
    __builtin_amdgcn_global_load_lds(
        (const __attribute__((address_space(1))) unsigned int*)gptr,
        (__attribute__((address_space(3))) unsigned int*)lptr, 16, 0, 0);
}

// ---------------------------------------------------------------------------
// Kernel 0: convert x -> bf16 (row-major), W -> bf16 TRANSPOSED [d][c],
// with 768^-0.5 folded into Wq.
// ---------------------------------------------------------------------------
__global__ __launch_bounds__(256) void convert_kernel(
    const float* __restrict__ x, const float* __restrict__ Wk,
    const float* __restrict__ Wq, const float* __restrict__ Wv,
    unsigned short* __restrict__ xb, unsigned short* __restrict__ wt)
{
    const int tid = blockIdx.x * 256 + threadIdx.x;
    const int NX4 = (NTOK * NEMBD) / 4;     // 3145728 float4 groups
    if (tid < NX4) {
        float4 v = ((const float4*)x)[tid];
        ((uint2*)xb)[tid] = make_uint2(pack2(v.x, v.y), pack2(v.z, v.w));
    } else {
        int i = tid - NX4;                  // 0..294911
        int w = i / (HDIM * NEMBD);         // which W
        int r = i % (HDIM * NEMBD);         // d*768 + c
        int d = r / NEMBD, c = r % NEMBD;
        const float* W = (w == 0) ? Wk : ((w == 1) ? Wq : Wv);
        float val = W[c * HDIM + d];
        if (w == 1) val *= 0.03608439182435161f;   // 768^-0.5
        wt[(size_t)w * (HDIM * NEMBD) + r] = f2bf(val);
    }
}

// ---------------------------------------------------------------------------
// Kernel 1: QKV GEMM, bf16 MFMA 32x32x16. 128x128 tile, BK=64,
// global_load_lds(16B) staging with XOR-chunk swizzle.
// y=0 -> kb [t][d], y=1 -> qb [t][d], y=2 -> vT [b][d][t]
// ---------------------------------------------------------------------------
__global__ __launch_bounds__(256) void gemm_qkv(
    const unsigned short* __restrict__ xb, const unsigned short* __restrict__ wt,
    unsigned short* __restrict__ kb, unsigned short* __restrict__ qb,
    unsigned short* __restrict__ vT)
{
    __shared__ __align__(16) char As[16384];   // 128 rows x 128 B (64 bf16)
    __shared__ __align__(16) char Bs[16384];   // 128 n-rows x 128 B

    const int tid = threadIdx.x, w = tid >> 6, lane = tid & 63;
    const int l31 = lane & 31, h = lane >> 5;
    const int r8 = lane >> 3, c8 = lane & 7;   // staging: 8 rows/call
    const int m0 = blockIdx.x * 128;
    const int y  = blockIdx.y;
    const unsigned short* Wt = wt + (size_t)y * (HDIM * NEMBD);

    floatx16 acc[4];
    #pragma unroll
    for (int nt = 0; nt < 4; ++nt)
        #pragma unroll
        for (int i = 0; i < 16; ++i) acc[nt][i] = 0.f;

    for (int it = 0; it < 12; ++it) {
        const int k0 = it * 64;
        __syncthreads();
        #pragma unroll
        for (int j = 0; j < 4; ++j) {
            int rowb = w * 32 + j * 8;
            int row  = rowb + r8;
            gl_lds16((const char*)xb + ((size_t)(m0 + row) * NEMBD + k0) * 2
                         + ((c8 ^ (row & 7)) * 16),
                     As + rowb * 128);
        }
        #pragma unroll
        for (int j = 0; j < 4; ++j) {
            int rowb = w * 32 + j * 8;
            int row  = rowb + r8;
            gl_lds16((const char*)Wt + ((size_t)row * NEMBD + k0) * 2
                         + ((c8 ^ (row & 7)) * 16),
                     Bs + rowb * 128);
        }
        __syncthreads();
        #pragma unroll
        for (int ks = 0; ks < 4; ++ks) {
            int arow = w * 32 + l31;
            short8 af = *(const short8*)(As + arow * 128 + (((2*ks + h) ^ (arow & 7)) * 16));
            #pragma unroll
            for (int nt = 0; nt < 4; ++nt) {
                int brow = nt * 32 + l31;
                short8 bf = *(const short8*)(Bs + brow * 128 + (((2*ks + h) ^ (brow & 7)) * 16));
                acc[nt] = MFMA32(af, bf, acc[nt]);
            }
        }
    }

    if (y < 2) {
        unsigned short* outp = (y == 0) ? kb : qb;
        #pragma unroll
        for (int nt = 0; nt < 4; ++nt) {
            int d = nt * 32 + l31;
            #pragma unroll
            for (int r = 0; r < 16; ++r) {
                int t = m0 + w * 32 + (r & 3) + 8 * (r >> 2) + 4 * h;
                outp[(size_t)t * HDIM + d] = f2bf(acc[nt][r]);
            }
        }
    } else {
        int b    = m0 >> 10;
        int tloc = m0 & 1023;
        #pragma unroll
        for (int nt = 0; nt < 4; ++nt) {
            int d = nt * 32 + l31;
            #pragma unroll
            for (int g = 0; g < 4; ++g) {
                int t = tloc + w * 32 + 8 * g + 4 * h;
                uint2 u = make_uint2(pack2(acc[nt][4*g+0], acc[nt][4*g+1]),
                                     pack2(acc[nt][4*g+2], acc[nt][4*g+3]));
                *(uint2*)((char*)vT + (((size_t)(b * HDIM + d)) * 1024 + t) * 2) = u;
            }
        }
    }
}

// ---------------------------------------------------------------------------
// Kernel 2: flash attention, bf16 MFMA. S^T = K*Q^T, O^T = V^T*P^T so that
// C-layout col = q-row = lane -> per-lane softmax state, no broadcasts.
// K/V fragments loaded directly from global (L2). No barriers in main loop.
// Grid (32 qt, 16 b), 4 waves split key-tiles (st = w, w+4, ...), LDS merge.
// ---------------------------------------------------------------------------
__global__ __launch_bounds__(256) void attn_mfma(
    const unsigned short* __restrict__ qb, const unsigned short* __restrict__ kb,
    const unsigned short* __restrict__ vT, float* __restrict__ out)
{
    __shared__ __align__(16) float Oacc[32 * 128];   // 16 KB merge buffer
    __shared__ float mred[128], lred[128], ltot[32];

    const int tid = threadIdx.x, w = tid >> 6, lane = tid & 63;
    const int l31 = lane & 31, h = lane >> 5;
    const int qt = blockIdx.x, b = blockIdx.y;

    const char* kb_b = (const char*)kb + (size_t)b * (1024 * 256);
    const char* qb_b = (const char*)qb + (size_t)b * (1024 * 256);
    const char* vT_b = (const char*)vT + (size_t)b * (HDIM * 2048);

    // Q fragments (B-operand, n = q = lane&31), loaded once
    short8 qf[8];
    {
        const char* qrow = qb_b + (size_t)(qt * 32 + l31) * 256 + h * 16;
        #pragma unroll
        for (int ks = 0; ks < 8; ++ks)
            qf[ks] = *(const short8*)(qrow + ks * 32);
    }

    floatx16 o[4];
    #pragma unroll
    for (int nt = 0; nt < 4; ++nt)
        #pragma unroll
        for (int i = 0; i < 16; ++i) o[nt][i] = 0.f;
    float m_r = -1e30f, l_r = 0.f;

    for (int st = w; st <= qt; st += 4) {
        // ---- S^T = K * Q^T  (A = K rows, m = key) ----
        const char* krow = kb_b + (size_t)(st * 32 + l31) * 256 + h * 16;
        floatx16 s;
        #pragma unroll
        for (int i = 0; i < 16; ++i) s[i] = 0.f;
        #pragma unroll
        for (int ks = 0; ks < 8; ++ks) {
            short8 kf = *(const short8*)(krow + ks * 32);
            s = MFMA32(kf, qf[ks], s);
        }
        if (st == qt) {            // causal mask on diagonal tile
            #pragma unroll
            for (int r = 0; r < 16; ++r) {
                int key = (r & 3) + 8 * (r >> 2) + 4 * h;
                if (key > l31) s[r] = -1e30f;
            }
        }
        // ---- online softmax (per-lane q = l31; halves hold disjoint keys) --
        float tmax = s[0];
        #pragma unroll
        for (int r = 1; r < 16; ++r) tmax = fmaxf(tmax, s[r]);
        tmax = fmaxf(tmax, __shfl_xor(tmax, 32, 64));
        float m_new = fmaxf(m_r, tmax);
        float p[16], psum = 0.f;
        #pragma unroll
        for (int r = 0; r < 16; ++r) { p[r] = __expf(s[r] - m_new); psum += p[r]; }
        psum += __shfl_xor(psum, 32, 64);
        float alpha = __expf(m_r - m_new);
        m_r = m_new;
        l_r = l_r * alpha + psum;

        // ---- P^T -> B-operand frags: pack bf16 pairs, cross-half exchange --
        unsigned own[8], rcv[8];
        #pragma unroll
        for (int i = 0; i < 8; ++i) own[i] = pack2(p[2*i], p[2*i+1]);
        #pragma unroll
        for (int i = 0; i < 8; ++i) rcv[i] = (unsigned)__shfl_xor((int)own[i], 32, 64);
        short8 pf[2];
        {
            union { short8 v; unsigned u[4]; } f0, f1;
            if (h == 0) {
                f0.u[0]=own[0]; f0.u[1]=own[1]; f0.u[2]=rcv[0]; f0.u[3]=rcv[1];
                f1.u[0]=own[4]; f1.u[1]=own[5]; f1.u[2]=rcv[4]; f1.u[3]=rcv[5];
            } else {
                f0.u[0]=rcv[2]; f0.u[1]=rcv[3]; f0.u[2]=own[2]; f0.u[3]=own[3];
                f1.u[0]=rcv[6]; f1.u[1]=rcv[7]; f1.u[2]=own[6]; f1.u[3]=own[7];
            }
            pf[0] = f0.v; pf[1] = f1.v;
        }
        // ---- O^T = O^T*alpha + V^T * P^T ----
        #pragma unroll
        for (int nt = 0; nt < 4; ++nt)
            #pragma unroll
            for (int i = 0; i < 16; ++i) o[nt][i] *= alpha;
        const char* vrow0 = vT_b + (size_t)l31 * 2048 + (size_t)st * 64 + h * 16;
        #pragma unroll
        for (int nt = 0; nt < 4; ++nt) {
            const char* vr = vrow0 + (size_t)nt * (32 * 2048);
            #pragma unroll
            for (int ks2 = 0; ks2 < 2; ++ks2) {
                short8 vf = *(const short8*)(vr + ks2 * 32);
                o[nt] = MFMA32(vf, pf[ks2], o[nt]);
            }
        }
    }

    // ---- merge the 4 waves' (m, l, O) ----
    if (lane < 32) { mred[w * 32 + l31] = m_r; lred[w * 32 + l31] = l_r; }
    __syncthreads();
    float M = fmaxf(fmaxf(mred[l31], mred[32 + l31]),
                    fmaxf(mred[64 + l31], mred[96 + l31]));
    float swv = __expf(m_r - M);
    if (w == 0 && lane < 32) {
        float lt = 0.f;
        #pragma unroll
        for (int i = 0; i < 4; ++i)
            lt += lred[i * 32 + l31] * __expf(mred[i * 32 + l31] - M);
        ltot[l31] = lt;
    }
    #pragma unroll
    for (int wv = 0; wv < 4; ++wv) {
        if (w == wv) {
            #pragma unroll
            for (int nt = 0; nt < 4; ++nt) {
                #pragma unroll
                for (int g = 0; g < 4; ++g) {
                    int chunk = nt * 8 + 2 * g + h;                  // d/4
                    int slot  = (chunk & 24) | ((chunk & 7) ^ (l31 & 7));
                    float4* p4 = (float4*)&Oacc[l31 * 128] + slot;
                    float4 vv = make_float4(o[nt][4*g+0]*swv, o[nt][4*g+1]*swv,
                                            o[nt][4*g+2]*swv, o[nt][4*g+3]*swv);
                    if (wv) {
                        float4 old = *p4;
                        vv.x += old.x; vv.y += old.y; vv.z += old.z; vv.w += old.w;
                    }
                    *p4 = vv;
                }
            }
        }
        __syncthreads();
    }
    // ---- final scale + coalesced store ----
    {
        int q  = tid >> 3;
        int cb = (tid & 7) * 4;
        float inv = 1.f / ltot[q];
        #pragma unroll
        for (int cc = 0; cc < 4; ++cc) {
            int chunk = cb + cc;
            int slot  = (chunk & 24) | ((chunk & 7) ^ (q & 7));
            float4 v = ((float4*)&Oacc[q * 128])[slot];
            v.x *= inv; v.y *= inv; v.z *= inv; v.w *= inv;
            *(float4*)&out[((size_t)(b * 1024 + qt * 32 + q)) * HDIM + chunk * 4] = v;
        }
    }
}

// ---------------------------------------------------------------------------
extern "C" void kernel_launch(void* const* d_in, const int* in_sizes, int n_in,
                              void* d_out, int out_size, void* d_ws, size_t ws_size,
                              hipStream_t stream)
{
    const float* x  = (const float*)d_in[0];
    const float* Wk = (const float*)d_in[1];
    const float* Wq = (const float*)d_in[2];
    const float* Wv = (const float*)d_in[3];
    float* outp = (float*)d_out;

    char* ws = (char*)d_ws;
    unsigned short* xb = (unsigned short*)(ws);                       // 25165824 B
    unsigned short* wt = (unsigned short*)(ws + 25165824);            //   589824 B
    unsigned short* kb = (unsigned short*)(ws + 25755648);            //  4194304 B
    unsigned short* qb = (unsigned short*)(ws + 29949952);            //  4194304 B
    unsigned short* vT = (unsigned short*)(ws + 34144256);            //  4194304 B

    convert_kernel<<<13440, 256, 0, stream>>>(x, Wk, Wq, Wv, xb, wt);
    gemm_qkv<<<dim3(128, 3), 256, 0, stream>>>(xb, wt, kb, qb, vT);
    attn_mfma<<<dim3(32, 16), 256, 0, stream>>>(qb, kb, vT, outp);
}